// Round 1
// baseline (215.932 us; speedup 1.0000x reference)
//
#include <hip/hip_runtime.h>
#include <hip/hip_cooperative_groups.h>

namespace cg = cooperative_groups;

// DSBatchNorm fused: N=16384 rows, F=1024 feats, D=8 domains.
// Single cooperative kernel, grid=256 blocks (1/CU) x 512 threads (8 waves/CU).
//   Phase 1: block b owns rows [b*64, b*64+64). Thread owns one float2 column.
//            Explicit double-buffered 8-row load pipeline -> per-domain s1/s2
//            in registers -> 64KB partials per block (16 MiB total, L3-hot).
//   Phase 2: 8192 (d,f) pairs / 256 blocks = 32 pairs each; 16 rg-chunks x 32
//            pairs across 512 threads, 16 loads in flight; LDS finish.
//            Counts + edge cases folded into scale/shift.
//   Phase 3: same block re-reads its own 64 rows (same XCD -> L2/L3 hit),
//            out = x*scale[y] + shift[y], non-temporal stores (out never read,
//            don't evict x/partials from L3 with output dirt).
// grid.sync() (cooperative) between phases replaces 2 kernel launches.

#define EPSV 1e-5f
constexpr int N = 16384;
constexpr int F = 1024;
constexpr int D = 8;
constexpr int NB = 256;       // blocks = CUs (cooperative residency: 1 block/CU)
constexpr int NT = 512;       // 8 waves/block
constexpr int RPB = N / NB;   // 64 rows per block
constexpr int F2 = F / 2;     // 512 float2 columns

typedef float f32x2 __attribute__((ext_vector_type(2)));

__global__ __launch_bounds__(NT, 2) void fused_dsbn(
    const float* __restrict__ x, const int* __restrict__ y,
    const float* __restrict__ gamma, const float* __restrict__ beta,
    float* __restrict__ out, float* __restrict__ partials,
    int* __restrict__ cnt_parts, float* __restrict__ scale,
    float* __restrict__ shift) {
  const int t = threadIdx.x;
  const int b = blockIdx.x;
  const int row0 = b * RPB;

  __shared__ int hist[D];
  __shared__ int sc[NB];
  __shared__ float sf[16][32][2];

  // ---------------- phase 1: per-block partial sums + histogram ----------------
  if (t < D) hist[t] = 0;
  __syncthreads();
  if (t < RPB) atomicAdd(&hist[y[row0 + t]], 1);

  float2 a1[D], a2[D];
#pragma unroll
  for (int k = 0; k < D; ++k) {
    a1[k] = make_float2(0.f, 0.f);
    a2[k] = make_float2(0.f, 0.f);
  }

  const float2* __restrict__ x2 = (const float2*)x;

#define ACC(K)                         \
  a1[K].x += v.x;                      \
  a1[K].y += v.y;                      \
  a2[K].x = fmaf(v.x, v.x, a2[K].x);   \
  a2[K].y = fmaf(v.y, v.y, a2[K].y);   \
  break;

  // double-buffered 8-row pipeline: prefetch group r+8 before consuming group r
  float2 vv[8];
  int dd[8];
#pragma unroll
  for (int j = 0; j < 8; ++j) {
    dd[j] = y[row0 + j];                              // uniform -> s_load
    vv[j] = x2[(size_t)(row0 + j) * F2 + t];          // 8 loads in flight
  }
#pragma unroll
  for (int r = 0; r < RPB; r += 8) {
    float2 nv[8];
    int nd[8];
    if (r + 8 < RPB) {
#pragma unroll
      for (int j = 0; j < 8; ++j) {
        nd[j] = y[row0 + r + 8 + j];
        nv[j] = x2[(size_t)(row0 + r + 8 + j) * F2 + t];
      }
    }
#pragma unroll
    for (int j = 0; j < 8; ++j) {
      float2 v = vv[j];
      switch (dd[j]) {
        case 0: ACC(0)
        case 1: ACC(1)
        case 2: ACC(2)
        case 3: ACC(3)
        case 4: ACC(4)
        case 5: ACC(5)
        case 6: ACC(6)
        case 7: ACC(7)
      }
    }
    if (r + 8 < RPB) {
#pragma unroll
      for (int j = 0; j < 8; ++j) {
        vv[j] = nv[j];
        dd[j] = nd[j];
      }
    }
  }
#undef ACC

  // partials as float4: p4[(b*D+k)*512 + t] = (s1.x, s2.x, s1.y, s2.y)
  // -> as float2 view: pf2[(rg*D+d)*1024 + f] = (s1[f], s2[f])
  float4* __restrict__ p4 = (float4*)partials;
#pragma unroll
  for (int k = 0; k < D; ++k)
    p4[(size_t)(b * D + k) * F2 + t] =
        make_float4(a1[k].x, a2[k].x, a1[k].y, a2[k].y);

  __syncthreads();
  if (t < D) cnt_parts[b * D + t] = hist[t];

  cg::this_grid().sync();

  // ---------------- phase 2: reduce partials -> scale/shift ----------------
  {
    const int i = t & 31;       // pair within block
    const int ch = t >> 5;      // rg-chunk 0..15
    const int p = b * 32 + i;   // flat (d,f)
    const int d = b >> 5;       // uniform per block (32 blocks per domain)
    const int f = p & (F - 1);

    if (t < NB) sc[t] = cnt_parts[t * D + d];

    const float2* __restrict__ pf2 = (const float2*)partials;
    float s1 = 0.f, s2 = 0.f;
#pragma unroll
    for (int r = 0; r < 16; ++r) {     // 16 loads fully in flight
      const int rg = ch * 16 + r;
      float2 v = pf2[(size_t)(rg * D + d) * F + f];
      s1 += v.x;
      s2 += v.y;
    }
    sf[ch][i][0] = s1;
    sf[ch][i][1] = s2;
    __syncthreads();
    for (int s = 128; s > 0; s >>= 1) {
      if (t < s) sc[t] += sc[t + s];
      __syncthreads();
    }

    if (t < 32) {
      float r1 = 0.f, r2 = 0.f;
#pragma unroll
      for (int c = 0; c < 16; ++c) {
        r1 += sf[c][t][0];
        r2 += sf[c][t][1];
      }
      const int pw = b * 32 + t;
      const float c = (float)sc[0];
      const float cc = fmaxf(c, 1.f);
      const float mean = r1 / cc;
      const float var = r2 / cc - mean * mean;
      const float inv = rsqrtf(var + EPSV);
      float scv = gamma[pw] * inv;
      float shv = beta[pw] - mean * scv;
      if (c <= 1.f) {  // count==1: passthrough x; count==0: zero output
        scv = (c == 1.f) ? 1.f : 0.f;
        shv = 0.f;
      }
      scale[pw] = scv;
      shift[pw] = shv;
    }
  }

  cg::this_grid().sync();

  // ---------------- phase 3: apply (same rows as phase 1 -> L2/L3 hit) ----------------
  {
    const float2* __restrict__ g2 = (const float2*)scale;
    const float2* __restrict__ h2 = (const float2*)shift;
    f32x2* __restrict__ o2 = (f32x2*)out;
#pragma unroll
    for (int r = 0; r < RPB; r += 8) {
      int dd2[8];
      float2 xv[8];
#pragma unroll
      for (int j = 0; j < 8; ++j) dd2[j] = y[row0 + r + j];   // uniform -> s_load
#pragma unroll
      for (int j = 0; j < 8; ++j)
        xv[j] = x2[(size_t)(row0 + r + j) * F2 + t];          // 8 loads in flight
#pragma unroll
      for (int j = 0; j < 8; ++j) {
        const float2 g = g2[dd2[j] * F2 + t];   // L2-hot (4 KB per domain)
        const float2 s = h2[dd2[j] * F2 + t];
        f32x2 o;
        o.x = fmaf(xv[j].x, g.x, s.x);
        o.y = fmaf(xv[j].y, g.y, s.y);
        __builtin_nontemporal_store(o, &o2[(size_t)(row0 + r + j) * F2 + t]);
      }
    }
  }
}

extern "C" void kernel_launch(void* const* d_in, const int* in_sizes, int n_in,
                              void* d_out, int out_size, void* d_ws, size_t ws_size,
                              hipStream_t stream) {
  const float* x = (const float*)d_in[0];
  const int* y = (const int*)d_in[1];
  const float* gamma = (const float*)d_in[2];
  const float* beta = (const float*)d_in[3];
  float* out = (float*)d_out;

  // ws layout (floats):
  //   partials : NB*D*F*2 = 4,194,304  (16 MiB)
  //   cnt_parts: NB*D ints =    2,048
  //   scale    : D*F       =    8,192
  //   shift    : D*F       =    8,192
  float* partials = (float*)d_ws;
  int* cnt_parts = (int*)(partials + (size_t)NB * D * F * 2);
  float* scale = (float*)(cnt_parts + NB * D);
  float* shift = scale + D * F;

  void* args[] = {(void*)&x,        (void*)&y,         (void*)&gamma,
                  (void*)&beta,     (void*)&out,       (void*)&partials,
                  (void*)&cnt_parts, (void*)&scale,    (void*)&shift};
  hipLaunchCooperativeKernel((const void*)fused_dsbn, dim3(NB), dim3(NT), args,
                             0, stream);
}

// Round 2
// 147.654 us; speedup vs baseline: 1.4624x; 1.4624x over previous
//
#include <hip/hip_runtime.h>

// DSBatchNorm: per-domain batch stats + affine. N=16384 rows, F=1024 feats, D=8 domains.
// 3 regular launches (cooperative fusion measured +65us fixed overhead in R1 — reverted).
// k1: 1024 blocks x 256 thr (4 blk/CU = 16 waves/CU), 32-row groups, explicit
//     double-buffered 8-row load pipeline -> per-domain s1/s2 in registers -> 32 MiB
//     partials (L3-resident). Per-rowgroup y-histograms (no global atomics/memset).
// k2: 1024 blocks x 256 thr, 512->1 reduction. Block owns 8 (d,f) pairs; 32 rg-chunks
//     of 16; 16 loads in flight/thread; 64B-line coalesced. Counts + edge cases folded
//     into scale/shift (branch-free k3).
// k3: out = x*scale[y] + shift[y]; 2048 blocks, 8 rows each, x loads batched 8-deep,
//     NON-TEMPORAL stores (out never re-read; don't evict L3-resident x with out dirt).

#define EPSV 1e-5f
constexpr int N = 16384;
constexpr int F = 1024;
constexpr int D = 8;
constexpr int RPB = 32;           // rows per rowgroup
constexpr int RG = N / RPB;       // 512 rowgroups
constexpr int F2 = F / 2;         // 512 float2 columns

typedef float f32x4 __attribute__((ext_vector_type(4)));

// ---------------- kernel 1: partial sums ----------------
// grid = RG*2 (2 column halves), block = 256. Thread owns 1 float2 of one half-row.
__global__ __launch_bounds__(256) void k1_partials(
    const float* __restrict__ x, const int* __restrict__ y,
    float* __restrict__ partials, int* __restrict__ cnt_parts) {
  const int t = threadIdx.x;
  const int rg = blockIdx.x >> 1;
  const int h = blockIdx.x & 1;
  const int row0 = rg * RPB;

  __shared__ int hist[D];
  if (t < D) hist[t] = 0;
  __syncthreads();
  if (h == 0 && t < RPB) atomicAdd(&hist[y[row0 + t]], 1);

  float2 a1[D], a2[D];
#pragma unroll
  for (int k = 0; k < D; ++k) {
    a1[k] = make_float2(0.f, 0.f);
    a2[k] = make_float2(0.f, 0.f);
  }

  const float2* __restrict__ x2 = (const float2*)x;
  const int c = h * 256 + t;  // float2 column, 0..511

#define ACC(K)                         \
  a1[K].x += v.x;                      \
  a1[K].y += v.y;                      \
  a2[K].x = fmaf(v.x, v.x, a2[K].x);   \
  a2[K].y = fmaf(v.y, v.y, a2[K].y);   \
  break;

  // explicit double-buffered 8-row pipeline (loads cannot sink into the switch)
  float2 vv[8];
  int dd[8];
#pragma unroll
  for (int j = 0; j < 8; ++j) {
    dd[j] = y[row0 + j];                          // uniform -> s_load
    vv[j] = x2[(size_t)(row0 + j) * F2 + c];      // 8 loads in flight
  }
#pragma unroll
  for (int r = 0; r < RPB; r += 8) {
    float2 nv[8];
    int nd[8];
    if (r + 8 < RPB) {
#pragma unroll
      for (int j = 0; j < 8; ++j) {
        nd[j] = y[row0 + r + 8 + j];
        nv[j] = x2[(size_t)(row0 + r + 8 + j) * F2 + c];
      }
    }
#pragma unroll
    for (int j = 0; j < 8; ++j) {
      float2 v = vv[j];
      switch (dd[j]) {
        case 0: ACC(0)
        case 1: ACC(1)
        case 2: ACC(2)
        case 3: ACC(3)
        case 4: ACC(4)
        case 5: ACC(5)
        case 6: ACC(6)
        case 7: ACC(7)
      }
    }
    if (r + 8 < RPB) {
#pragma unroll
      for (int j = 0; j < 8; ++j) {
        vv[j] = nv[j];
        dd[j] = nd[j];
      }
    }
  }
#undef ACC

  // partials float2-view: pp2[(rg*D + d)*1024 + f] = (s1[f], s2[f])
  float4* __restrict__ p4 = (float4*)partials;
#pragma unroll
  for (int k = 0; k < D; ++k)
    p4[(size_t)(rg * D + k) * F2 + c] =
        make_float4(a1[k].x, a2[k].x, a1[k].y, a2[k].y);

  __syncthreads();
  if (h == 0 && t < D) cnt_parts[rg * D + t] = hist[t];
}

// ---------------- kernel 2: full stats reduction -> scale/shift ----------------
// grid = 1024 blocks x 256 thr. Block b owns 8 pairs p = b*8 + (t&7); d uniform
// per block. Thread reduces rg-chunk (t>>3): 16 float2 loads in flight; lane
// groups of 8 read one full 64B line. LDS finishes 32 chunks.
__global__ __launch_bounds__(256) void k2_stats(
    const float* __restrict__ partials, const int* __restrict__ cnt_parts,
    const float* __restrict__ gamma, const float* __restrict__ beta,
    float* __restrict__ scale, float* __restrict__ shift) {
  const int t = threadIdx.x;
  const int i = t & 7;          // pair within block
  const int ch = t >> 3;        // rg-chunk, 0..31
  const int p = blockIdx.x * 8 + i;  // flat (d,f), 0..8191
  const int d = p >> 10;        // uniform per block (8 | 1024)

  __shared__ int sc[256];
  sc[t] = cnt_parts[t * D + d] + cnt_parts[(t + 256) * D + d];

  const float2* __restrict__ pp = (const float2*)partials;
  float s1 = 0.f, s2 = 0.f;
#pragma unroll
  for (int r = 0; r < 16; ++r) {
    const int rg = ch * 16 + r;
    float2 v = pp[(size_t)rg * (D * F) + p];
    s1 += v.x;
    s2 += v.y;
  }

  __shared__ float sf[32][8][2];
  sf[ch][i][0] = s1;
  sf[ch][i][1] = s2;
  __syncthreads();
  for (int s = 128; s > 0; s >>= 1) {
    if (t < s) sc[t] += sc[t + s];
    __syncthreads();
  }

  if (t < 8) {
    float r1 = 0.f, r2 = 0.f;
#pragma unroll
    for (int c = 0; c < 32; ++c) {
      r1 += sf[c][t][0];
      r2 += sf[c][t][1];
    }
    const int pw = blockIdx.x * 8 + t;
    const float c = (float)sc[0];
    const float cc = fmaxf(c, 1.f);
    const float mean = r1 / cc;
    const float var = r2 / cc - mean * mean;
    const float inv = rsqrtf(var + EPSV);
    float scv = gamma[pw] * inv;
    float shv = beta[pw] - mean * scv;
    if (c <= 1.f) {  // count==1: passthrough x; count==0: zero output
      scv = (c == 1.f) ? 1.f : 0.f;
      shv = 0.f;
    }
    scale[pw] = scv;
    shift[pw] = shv;
  }
}

// ---------------- kernel 3: apply ----------------
// grid = N/8 = 2048 blocks, block = 256; 8 rows/block, one float4 per thread per
// row. x loads batched 8-deep; non-temporal float4 stores.
__global__ __launch_bounds__(256) void k3_apply(
    const float* __restrict__ x, const int* __restrict__ y,
    const float* __restrict__ scale, const float* __restrict__ shift,
    float* __restrict__ out) {
  const int t = threadIdx.x;
  const int n0 = blockIdx.x * 8;

  int dd[8];
#pragma unroll
  for (int j = 0; j < 8; ++j) dd[j] = y[n0 + j];  // uniform -> s_load

  float4 xv[8];
#pragma unroll
  for (int j = 0; j < 8; ++j)
    xv[j] = ((const float4*)x)[(size_t)(n0 + j) * 256 + t];  // 8 loads in flight

  f32x4* __restrict__ o4 = (f32x4*)out;
#pragma unroll
  for (int j = 0; j < 8; ++j) {
    const float4 g = ((const float4*)scale)[dd[j] * 256 + t];  // L2/L3-hot
    const float4 b = ((const float4*)shift)[dd[j] * 256 + t];
    f32x4 o;
    o.x = fmaf(xv[j].x, g.x, b.x);
    o.y = fmaf(xv[j].y, g.y, b.y);
    o.z = fmaf(xv[j].z, g.z, b.z);
    o.w = fmaf(xv[j].w, g.w, b.w);
    __builtin_nontemporal_store(o, &o4[(size_t)(n0 + j) * 256 + t]);
  }
}

extern "C" void kernel_launch(void* const* d_in, const int* in_sizes, int n_in,
                              void* d_out, int out_size, void* d_ws, size_t ws_size,
                              hipStream_t stream) {
  const float* x = (const float*)d_in[0];
  const int* y = (const int*)d_in[1];
  const float* gamma = (const float*)d_in[2];
  const float* beta = (const float*)d_in[3];
  float* out = (float*)d_out;

  // ws layout (floats):
  //   partials : RG*D*F*2 = 8,388,608  (32 MiB)
  //   cnt_parts: RG*D ints =    4,096
  //   scale    : D*F       =    8,192
  //   shift    : D*F       =    8,192
  float* partials = (float*)d_ws;
  int* cnt_parts = (int*)(partials + (size_t)RG * D * F * 2);
  float* scale = (float*)(cnt_parts + RG * D);
  float* shift = scale + D * F;

  k1_partials<<<RG * 2, 256, 0, stream>>>(x, y, partials, cnt_parts);
  k2_stats<<<1024, 256, 0, stream>>>(partials, cnt_parts, gamma, beta, scale, shift);
  k3_apply<<<N / 8, 256, 0, stream>>>(x, y, scale, shift, out);
}

// Round 3
// 134.789 us; speedup vs baseline: 1.6020x; 1.0954x over previous
//
#include <hip/hip_runtime.h>

// DSBatchNorm: per-domain batch stats + affine. N=16384 rows, F=1024 feats, D=8 domains.
// Budget analysis (R0-R2): ~96us is harness-fixed (256MiB ws-poison fill ~41us + reset
// memset/restore dispatches ~55us). Our 3 kernels are ~40us vs ~32us floor.
// R1 lesson: cooperative fusion costs +65us fixed -> 3 regular launches.
// R2 lesson: 32MiB partials (+5us) and NT stores (+6us) both regress -> reverted.
// k1: 512 blocks x 256 thr (2 blk/CU, 8 waves/CU), 64-row groups, 16-deep
//     double-buffered load pipeline, per-domain s1/s2 in registers, 16 MiB partials.
// k2: 512 blocks x 256 thr (2 blk/CU), block owns 16 (d,f) pairs, 16 rg-chunks of 16,
//     16 loads in flight. Counts + edge cases folded into scale/shift.
// k3: out = x*scale[y] + shift[y]; 2048 blocks, 8 rows each, batch-8 float4 loads,
//     regular (cache-allocating) stores — x is L3-resident from k1, write-bound ~11us.

#define EPSV 1e-5f
constexpr int N = 16384;
constexpr int F = 1024;
constexpr int D = 8;
constexpr int RPB = 64;           // rows per rowgroup
constexpr int RG = N / RPB;       // 256 rowgroups
constexpr int F2 = F / 2;         // 512 float2 columns

// ---------------- kernel 1: partial sums ----------------
// grid = RG*2 (2 column halves), block = 256. Thread owns 1 float2 of one half-row.
__global__ __launch_bounds__(256) void k1_partials(
    const float* __restrict__ x, const int* __restrict__ y,
    float* __restrict__ partials, int* __restrict__ cnt_parts) {
  const int t = threadIdx.x;
  const int rg = blockIdx.x >> 1;
  const int h = blockIdx.x & 1;
  const int row0 = rg * RPB;

  __shared__ int hist[D];
  if (t < D) hist[t] = 0;
  __syncthreads();
  if (h == 0 && t < RPB) atomicAdd(&hist[y[row0 + t]], 1);

  float2 a1[D], a2[D];
#pragma unroll
  for (int k = 0; k < D; ++k) {
    a1[k] = make_float2(0.f, 0.f);
    a2[k] = make_float2(0.f, 0.f);
  }

  const float2* __restrict__ x2 = (const float2*)x;
  const int c = h * 256 + t;  // float2 column, 0..511

#define ACC(K)                         \
  a1[K].x += v.x;                      \
  a1[K].y += v.y;                      \
  a2[K].x = fmaf(v.x, v.x, a2[K].x);   \
  a2[K].y = fmaf(v.y, v.y, a2[K].y);   \
  break;

  // 16-deep steady state: consume batch r while batch r+8 is in flight.
  float2 vv[8];
  int dd[8];
#pragma unroll
  for (int j = 0; j < 8; ++j) {
    dd[j] = y[row0 + j];                          // uniform -> s_load
    vv[j] = x2[(size_t)(row0 + j) * F2 + c];
  }
#pragma unroll
  for (int r = 0; r < RPB; r += 8) {
    float2 nv[8];
    int nd[8];
    if (r + 8 < RPB) {
#pragma unroll
      for (int j = 0; j < 8; ++j) {
        nd[j] = y[row0 + r + 8 + j];
        nv[j] = x2[(size_t)(row0 + r + 8 + j) * F2 + c];
      }
    }
#pragma unroll
    for (int j = 0; j < 8; ++j) {
      float2 v = vv[j];
      switch (dd[j]) {
        case 0: ACC(0)
        case 1: ACC(1)
        case 2: ACC(2)
        case 3: ACC(3)
        case 4: ACC(4)
        case 5: ACC(5)
        case 6: ACC(6)
        case 7: ACC(7)
      }
    }
    if (r + 8 < RPB) {
#pragma unroll
      for (int j = 0; j < 8; ++j) {
        vv[j] = nv[j];
        dd[j] = nd[j];
      }
    }
  }
#undef ACC

  // partials float2-view: pp2[(rg*D + d)*1024 + f] = (s1[f], s2[f])
  float4* __restrict__ p4 = (float4*)partials;
#pragma unroll
  for (int k = 0; k < D; ++k)
    p4[(size_t)(rg * D + k) * F2 + c] =
        make_float4(a1[k].x, a2[k].x, a1[k].y, a2[k].y);

  __syncthreads();
  if (h == 0 && t < D) cnt_parts[rg * D + t] = hist[t];
}

// ---------------- kernel 2: full stats reduction -> scale/shift ----------------
// grid = 512 blocks x 256 thr (2 blk/CU). Block b owns 16 pairs p = b*16 + (t&15);
// d uniform per block (16 | 1024). Thread reduces rg-chunk (t>>4): 16 float2 loads
// in flight, lane groups of 16 read 128B contiguous. LDS finishes 16 chunks.
__global__ __launch_bounds__(256) void k2_stats(
    const float* __restrict__ partials, const int* __restrict__ cnt_parts,
    const float* __restrict__ gamma, const float* __restrict__ beta,
    float* __restrict__ scale, float* __restrict__ shift) {
  const int t = threadIdx.x;
  const int i = t & 15;          // pair within block
  const int ch = t >> 4;         // rg-chunk, 0..15
  const int p = blockIdx.x * 16 + i;  // flat (d,f), 0..8191
  const int d = p >> 10;         // uniform per block

  __shared__ int sc[256];
  sc[t] = cnt_parts[t * D + d];

  const float2* __restrict__ pp = (const float2*)partials;
  float s1 = 0.f, s2 = 0.f;
#pragma unroll
  for (int r = 0; r < 16; ++r) {     // 16 loads fully in flight
    const int rg = ch * 16 + r;
    float2 v = pp[(size_t)rg * (D * F) + p];
    s1 += v.x;
    s2 += v.y;
  }

  __shared__ float sf[16][16][2];
  sf[ch][i][0] = s1;
  sf[ch][i][1] = s2;
  __syncthreads();
  for (int s = 128; s > 0; s >>= 1) {
    if (t < s) sc[t] += sc[t + s];
    __syncthreads();
  }

  if (t < 16) {
    float r1 = 0.f, r2 = 0.f;
#pragma unroll
    for (int c = 0; c < 16; ++c) {
      r1 += sf[c][t][0];
      r2 += sf[c][t][1];
    }
    const int pw = blockIdx.x * 16 + t;
    const float c = (float)sc[0];
    const float cc = fmaxf(c, 1.f);
    const float mean = r1 / cc;
    const float var = r2 / cc - mean * mean;
    const float inv = rsqrtf(var + EPSV);
    float scv = gamma[pw] * inv;
    float shv = beta[pw] - mean * scv;
    if (c <= 1.f) {  // count==1: passthrough x; count==0: zero output
      scv = (c == 1.f) ? 1.f : 0.f;
      shv = 0.f;
    }
    scale[pw] = scv;
    shift[pw] = shv;
  }
}

// ---------------- kernel 3: apply ----------------
// grid = N/8 = 2048 blocks, block = 256; 8 rows/block, one float4 per thread per
// row. x loads batched 8-deep (128B/thread in flight); regular stores.
__global__ __launch_bounds__(256) void k3_apply(
    const float* __restrict__ x, const int* __restrict__ y,
    const float* __restrict__ scale, const float* __restrict__ shift,
    float* __restrict__ out) {
  const int t = threadIdx.x;
  const int n0 = blockIdx.x * 8;

  int dd[8];
#pragma unroll
  for (int j = 0; j < 8; ++j) dd[j] = y[n0 + j];  // uniform -> s_load

  float4 xv[8];
#pragma unroll
  for (int j = 0; j < 8; ++j)
    xv[j] = ((const float4*)x)[(size_t)(n0 + j) * 256 + t];  // 8 loads in flight

#pragma unroll
  for (int j = 0; j < 8; ++j) {
    const float4 g = ((const float4*)scale)[dd[j] * 256 + t];  // L2-hot
    const float4 b = ((const float4*)shift)[dd[j] * 256 + t];
    float4 o;
    o.x = fmaf(xv[j].x, g.x, b.x);
    o.y = fmaf(xv[j].y, g.y, b.y);
    o.z = fmaf(xv[j].z, g.z, b.z);
    o.w = fmaf(xv[j].w, g.w, b.w);
    ((float4*)out)[(size_t)(n0 + j) * 256 + t] = o;
  }
}

extern "C" void kernel_launch(void* const* d_in, const int* in_sizes, int n_in,
                              void* d_out, int out_size, void* d_ws, size_t ws_size,
                              hipStream_t stream) {
  const float* x = (const float*)d_in[0];
  const int* y = (const int*)d_in[1];
  const float* gamma = (const float*)d_in[2];
  const float* beta = (const float*)d_in[3];
  float* out = (float*)d_out;

  // ws layout (floats):
  //   partials : RG*D*F*2 = 4,194,304  (16 MiB)
  //   cnt_parts: RG*D ints =    2,048
  //   scale    : D*F       =    8,192
  //   shift    : D*F       =    8,192
  float* partials = (float*)d_ws;
  int* cnt_parts = (int*)(partials + (size_t)RG * D * F * 2);
  float* scale = (float*)(cnt_parts + RG * D);
  float* shift = scale + D * F;

  k1_partials<<<RG * 2, 256, 0, stream>>>(x, y, partials, cnt_parts);
  k2_stats<<<512, 256, 0, stream>>>(partials, cnt_parts, gamma, beta, scale, shift);
  k3_apply<<<N / 8, 256, 0, stream>>>(x, y, scale, shift, out);
}

// Round 5
// 132.376 us; speedup vs baseline: 1.6312x; 1.0182x over previous
//
#include <hip/hip_runtime.h>

// DSBatchNorm: per-domain batch stats + affine. N=16384 rows, F=1024 feats, D=8 domains.
// Budget (R0-R3): ~96us harness-fixed (256MiB ws-poison fill ~41us + reset dispatches),
// our 3 kernels ~40us vs ~32us floor. R1: cooperative fusion = +65us fixed (reverted).
// R2: 32MiB partials / NT stores regress (reverted). R3: pipeline depth = no effect.
// R4 lever: shrink partials RT 16MiB->4MiB. Rowgroups grow to 256 rows (RG=64) but
// split over 8 column-chunk blocks -> grid stays 512, per-thread accumulates 64 rows,
// 32KB LDS reduce folds 4 row-subsets before the global write.
// (R4 bench was an infra failure — container acquisition; source re-audited for
//  divergent-barrier hangs and ws overrun: none. Resubmitted unchanged.)
// k1: 512 blocks (64 rg x 8 col-chunks) x 256 thr; per-domain s1/s2 in regs;
//     LDS 4-subset reduce; 8KB partials out per block (4 MiB total, L3-hot).
// k2: 256 blocks x 256 thr; block owns 32 (d,f) pairs, 8 rg-chunks of 8; counts +
//     edge cases folded into scale/shift (branch-free k3).
// k3: out = x*scale[y] + shift[y]; 2048 blocks, 8 rows, batch-8 float4 loads,
//     regular cache-allocating stores (x L3-resident from k1).

#define EPSV 1e-5f
constexpr int N = 16384;
constexpr int F = 1024;
constexpr int D = 8;
constexpr int RPG = 256;          // rows per rowgroup
constexpr int RG = N / RPG;       // 64 rowgroups
constexpr int F2 = F / 2;         // 512 float2 columns
constexpr int CCH = 8;            // column chunks per rowgroup
constexpr int CW = F2 / CCH;      // 64 float2 cols per chunk

// ---------------- kernel 1: partial sums ----------------
// Block (rg, chunk): rows [rg*256, +256), float2 cols [chunk*64, +64).
// Thread t: col = chunk*64 + (t&63), row-subset (t>>6) owns 64 rows.
__global__ __launch_bounds__(256) void k1_partials(
    const float* __restrict__ x, const int* __restrict__ y,
    float* __restrict__ partials, int* __restrict__ cnt_parts) {
  const int t = threadIdx.x;
  const int rg = blockIdx.x >> 3;     // 0..63
  const int chunk = blockIdx.x & 7;   // 0..7
  const int row0 = rg * RPG;
  const int cl = t & 63;              // col within chunk
  const int sub = t >> 6;             // row subset 0..3 (uniform per wave)
  const int c = chunk * CW + cl;      // global float2 col

  __shared__ int hist[D];
  if (t < D) hist[t] = 0;
  __syncthreads();
  if (chunk == 0) atomicAdd(&hist[y[row0 + t]], 1);  // 256 rows, one chunk only

  float2 a1[D], a2[D];
#pragma unroll
  for (int k = 0; k < D; ++k) {
    a1[k] = make_float2(0.f, 0.f);
    a2[k] = make_float2(0.f, 0.f);
  }

  const float2* __restrict__ x2 = (const float2*)x;
  const int rbase = row0 + sub * 64;

#define ACC(K)                         \
  a1[K].x += v.x;                      \
  a1[K].y += v.y;                      \
  a2[K].x = fmaf(v.x, v.x, a2[K].x);   \
  a2[K].y = fmaf(v.y, v.y, a2[K].y);   \
  break;

  // 8-deep double-buffered pipeline over this subset's 64 rows
  float2 vv[8];
  int dd[8];
#pragma unroll
  for (int j = 0; j < 8; ++j) {
    dd[j] = y[rbase + j];                          // uniform per wave -> s_load
    vv[j] = x2[(size_t)(rbase + j) * F2 + c];
  }
#pragma unroll
  for (int r = 0; r < 64; r += 8) {
    float2 nv[8];
    int nd[8];
    if (r + 8 < 64) {
#pragma unroll
      for (int j = 0; j < 8; ++j) {
        nd[j] = y[rbase + r + 8 + j];
        nv[j] = x2[(size_t)(rbase + r + 8 + j) * F2 + c];
      }
    }
#pragma unroll
    for (int j = 0; j < 8; ++j) {
      float2 v = vv[j];
      switch (dd[j]) {
        case 0: ACC(0)
        case 1: ACC(1)
        case 2: ACC(2)
        case 3: ACC(3)
        case 4: ACC(4)
        case 5: ACC(5)
        case 6: ACC(6)
        case 7: ACC(7)
      }
    }
    if (r + 8 < 64) {
#pragma unroll
      for (int j = 0; j < 8; ++j) {
        vv[j] = nv[j];
        dd[j] = nd[j];
      }
    }
  }
#undef ACC

  // fold the 4 row-subsets in LDS (32 KB), then one 8KB global write per block
  __shared__ float4 red[4][D][CW];
#pragma unroll
  for (int k = 0; k < D; ++k)
    red[sub][k][cl] = make_float4(a1[k].x, a2[k].x, a1[k].y, a2[k].y);
  __syncthreads();

  // partials float2-view: pp2[(rg*D + d)*1024 + f] = (s1[f], s2[f])
  float4* __restrict__ p4 = (float4*)partials;
#pragma unroll
  for (int u = 0; u < 2; ++u) {
    const int idx = t * 2 + u;        // 0..511 = (d, col)
    const int d = idx >> 6;
    const int col = idx & 63;
    const float4 v0 = red[0][d][col];
    const float4 v1 = red[1][d][col];
    const float4 v2 = red[2][d][col];
    const float4 v3 = red[3][d][col];
    float4 w;
    w.x = (v0.x + v1.x) + (v2.x + v3.x);
    w.y = (v0.y + v1.y) + (v2.y + v3.y);
    w.z = (v0.z + v1.z) + (v2.z + v3.z);
    w.w = (v0.w + v1.w) + (v2.w + v3.w);
    p4[(size_t)(rg * D + d) * F2 + chunk * CW + col] = w;
  }

  if (chunk == 0 && t < D) cnt_parts[rg * D + t] = hist[t];
}

// ---------------- kernel 2: full stats reduction -> scale/shift ----------------
// grid = 256 blocks x 256 thr. Block owns 32 pairs p = b*32 + (t&31); d uniform
// per block (32 | 1024). Thread reduces rg-chunk (t>>5): 8 float2 loads in flight,
// lane groups of 32 read 256B contiguous. LDS finishes 8 chunks.
__global__ __launch_bounds__(256) void k2_stats(
    const float* __restrict__ partials, const int* __restrict__ cnt_parts,
    const float* __restrict__ gamma, const float* __restrict__ beta,
    float* __restrict__ scale, float* __restrict__ shift) {
  const int t = threadIdx.x;
  const int i = t & 31;          // pair within block
  const int ch = t >> 5;         // rg-chunk, 0..7
  const int p = blockIdx.x * 32 + i;  // flat (d,f), 0..8191
  const int d = p >> 10;         // uniform per block

  __shared__ int sc[RG];
  if (t < RG) sc[t] = cnt_parts[t * D + d];

  const float2* __restrict__ pp = (const float2*)partials;
  float s1 = 0.f, s2 = 0.f;
#pragma unroll
  for (int r = 0; r < 8; ++r) {      // 8 loads fully in flight
    const int rg = ch * 8 + r;
    float2 v = pp[(size_t)rg * (D * F) + p];
    s1 += v.x;
    s2 += v.y;
  }

  __shared__ float sf[8][32][2];
  sf[ch][i][0] = s1;
  sf[ch][i][1] = s2;
  __syncthreads();
  for (int s = 32; s > 0; s >>= 1) {
    if (t < s) sc[t] += sc[t + s];
    __syncthreads();
  }

  if (t < 32) {
    float r1 = 0.f, r2 = 0.f;
#pragma unroll
    for (int c = 0; c < 8; ++c) {
      r1 += sf[c][t][0];
      r2 += sf[c][t][1];
    }
    const int pw = blockIdx.x * 32 + t;
    const float c = (float)sc[0];
    const float cc = fmaxf(c, 1.f);
    const float mean = r1 / cc;
    const float var = r2 / cc - mean * mean;
    const float inv = rsqrtf(var + EPSV);
    float scv = gamma[pw] * inv;
    float shv = beta[pw] - mean * scv;
    if (c <= 1.f) {  // count==1: passthrough x; count==0: zero output
      scv = (c == 1.f) ? 1.f : 0.f;
      shv = 0.f;
    }
    scale[pw] = scv;
    shift[pw] = shv;
  }
}

// ---------------- kernel 3: apply ----------------
// grid = N/8 = 2048 blocks, block = 256; 8 rows/block, one float4 per thread per
// row. x loads batched 8-deep; regular stores.
__global__ __launch_bounds__(256) void k3_apply(
    const float* __restrict__ x, const int* __restrict__ y,
    const float* __restrict__ scale, const float* __restrict__ shift,
    float* __restrict__ out) {
  const int t = threadIdx.x;
  const int n0 = blockIdx.x * 8;

  int dd[8];
#pragma unroll
  for (int j = 0; j < 8; ++j) dd[j] = y[n0 + j];  // uniform -> s_load

  float4 xv[8];
#pragma unroll
  for (int j = 0; j < 8; ++j)
    xv[j] = ((const float4*)x)[(size_t)(n0 + j) * 256 + t];  // 8 loads in flight

#pragma unroll
  for (int j = 0; j < 8; ++j) {
    const float4 g = ((const float4*)scale)[dd[j] * 256 + t];  // L2-hot
    const float4 b = ((const float4*)shift)[dd[j] * 256 + t];
    float4 o;
    o.x = fmaf(xv[j].x, g.x, b.x);
    o.y = fmaf(xv[j].y, g.y, b.y);
    o.z = fmaf(xv[j].z, g.z, b.z);
    o.w = fmaf(xv[j].w, g.w, b.w);
    ((float4*)out)[(size_t)(n0 + j) * 256 + t] = o;
  }
}

extern "C" void kernel_launch(void* const* d_in, const int* in_sizes, int n_in,
                              void* d_out, int out_size, void* d_ws, size_t ws_size,
                              hipStream_t stream) {
  const float* x = (const float*)d_in[0];
  const int* y = (const int*)d_in[1];
  const float* gamma = (const float*)d_in[2];
  const float* beta = (const float*)d_in[3];
  float* out = (float*)d_out;

  // ws layout (floats):
  //   partials : RG*D*F*2 = 1,048,576  (4 MiB)
  //   cnt_parts: RG*D ints =      512
  //   scale    : D*F       =    8,192
  //   shift    : D*F       =    8,192
  float* partials = (float*)d_ws;
  int* cnt_parts = (int*)(partials + (size_t)RG * D * F * 2);
  float* scale = (float*)(cnt_parts + RG * D);
  float* shift = scale + D * F;

  k1_partials<<<RG * CCH, 256, 0, stream>>>(x, y, partials, cnt_parts);
  k2_stats<<<256, 256, 0, stream>>>(partials, cnt_parts, gamma, beta, scale, shift);
  k3_apply<<<N / 8, 256, 0, stream>>>(x, y, scale, shift, out);
}